// Round 1
// baseline (536.954 us; speedup 1.0000x reference)
//
#include <hip/hip_runtime.h>
#include <math.h>

#define NN 8192
#define FIN 128
#define FOUT 64
#define LRELU 0.2f
#define JSPLIT 8
#define BI 128
#define BJ 64
#define PSTR 65   // 64 + 1 pad: breaks power-of-2 LDS strides (2-way max)

// workspace layout (float offsets)
#define WS_H 0
#define WS_S1 (NN * FOUT)              // 524288
#define WS_S2 (WS_S1 + NN)             // 532480
#define WS_S2MAX (WS_S2 + NN)          // 540672
#define WS_PACC 540688                 // 16B aligned
#define WS_LP (WS_PACC + JSPLIT * NN * FOUT)

// ---------------------------------------------------------------------------
// Kernel 1: h = x @ W  (8192x128 @ 128x64), s1 = h@a1, s2 = h@a2
// block = 256 threads = 4 rows x 64 feats; one wave per row.
// ---------------------------------------------------------------------------
__global__ __launch_bounds__(256) void k_hs(const float* __restrict__ x,
                                            const float* __restrict__ W,
                                            const float* __restrict__ a,
                                            float* ws) {
  __shared__ float Wl[FIN * FOUT];   // 32 KB
  __shared__ float xl[4 * FIN];      // 2 KB
  const int t = threadIdx.x;
  const int i0 = blockIdx.x * 4;

#pragma unroll
  for (int c = 0; c < 8; ++c) {
    const int flat = c * 1024 + t * 4;
    *(float4*)&Wl[flat] = *(const float4*)&W[flat];
  }
  {
    const int flat = t * 2;  // 512 floats = 4 rows x 128
    *(float2*)&xl[flat] = *(const float2*)&x[(size_t)i0 * FIN + flat];
  }
  __syncthreads();

  const int r = t >> 6;   // wave index == local row
  const int f = t & 63;   // feature = lane
  float acc = 0.f;
#pragma unroll 8
  for (int k = 0; k < FIN; ++k)
    acc = fmaf(xl[r * FIN + k], Wl[k * FOUT + f], acc);

  ws[WS_H + (size_t)(i0 + r) * FOUT + f] = acc;

  float v1 = acc * a[f];
  float v2 = acc * a[FOUT + f];
#pragma unroll
  for (int off = 32; off >= 1; off >>= 1) {
    v1 += __shfl_xor(v1, off);
    v2 += __shfl_xor(v2, off);
  }
  if (f == 0) {
    ws[WS_S1 + i0 + r] = v1;
    ws[WS_S2 + i0 + r] = v2;
  }
}

// ---------------------------------------------------------------------------
// Kernel 2: S2max = max_j s2[j]  (global scalar -> closed-form row max m_i)
// ---------------------------------------------------------------------------
__global__ __launch_bounds__(256) void k_s2max(float* ws) {
  __shared__ float red[256];
  const int t = threadIdx.x;
  float v = -1e30f;
  for (int i = t; i < NN; i += 256) v = fmaxf(v, ws[WS_S2 + i]);
  red[t] = v;
  __syncthreads();
  for (int s = 128; s >= 1; s >>= 1) {
    if (t < s) red[t] = fmaxf(red[t], red[t + s]);
    __syncthreads();
  }
  if (t == 0) ws[WS_S2MAX] = red[0];
}

// ---------------------------------------------------------------------------
// Kernel 3: main fused pass. Block = 128 threads, tile = BI(128) rows x
// full j-chunk (1024 per j-split). Single pass over adj:
//   p_ij = adj ? exp(leaky(s1_i+s2_j) - m_i) : 0
//   lacc_i += p_ij ; acc_if += p_ij * h_jf
// 8x8 register micro-tile for the P@H contraction.
// ---------------------------------------------------------------------------
__global__ __launch_bounds__(128) void k_main(const int* __restrict__ adj,
                                              float* ws) {
  __shared__ float hl[BJ * FOUT];      // 16 KB
  __shared__ float pl[BI * PSTR];      // 33.3 KB
  __shared__ float s1l[BI], mll[BI];

  const int t = threadIdx.x;
  const int ib = blockIdx.x >> 3;
  const int js = blockIdx.x & 7;
  const int i0 = ib * BI;
  const int jbase = js * (NN / JSPLIT);   // 1024-wide j-chunk

  const float s2max = ws[WS_S2MAX];
  {
    const float s1v = ws[WS_S1 + i0 + t];     // t in [0,128) == BI
    const float tmp = s1v + s2max;
    s1l[t] = s1v;
    mll[t] = fmaxf(tmp, LRELU * tmp);         // leaky is max(x, 0.2x)
  }

  float4 acc[8][2];
#pragma unroll
  for (int r = 0; r < 8; ++r) {
    acc[r][0] = make_float4(0.f, 0.f, 0.f, 0.f);
    acc[r][1] = make_float4(0.f, 0.f, 0.f, 0.f);
  }
  float lacc[16];
#pragma unroll
  for (int c = 0; c < 16; ++c) lacc[c] = 0.f;

  const int tf = t & 7;    // feat group: feats [8*tf, 8*tf+8)
  const int tr = t >> 3;   // row group:  rows  [8*tr, 8*tr+8)
  const int t4 = t & 15;   // p-compute j-group
  const int r16 = t >> 4;  // p-compute i offset

  __syncthreads();

  for (int tile = 0; tile < (NN / JSPLIT) / BJ; ++tile) {  // 16 tiles
    const int j0 = jbase + tile * BJ;

    // stage h tile (64x64), coalesced float4
#pragma unroll
    for (int c = 0; c < 8; ++c) {
      const int flat = c * 512 + t * 4;
      *(float4*)&hl[flat] = *(const float4*)&ws[WS_H + (size_t)j0 * FOUT + flat];
    }

    // p tile: each thread covers 16 i's x 4 consecutive j's
    const float4 s2v = *(const float4*)&ws[WS_S2 + j0 + t4 * 4];
#pragma unroll
    for (int c = 0; c < 16; ++c) {
      const int il = c * 8 + r16;
      const int4 av = *(const int4*)&adj[(size_t)(i0 + il) * NN + j0 + t4 * 4];
      const float s1v = s1l[il], mv = mll[il];
      float e0 = s1v + s2v.x; e0 = fmaxf(e0, LRELU * e0);
      float e1 = s1v + s2v.y; e1 = fmaxf(e1, LRELU * e1);
      float e2 = s1v + s2v.z; e2 = fmaxf(e2, LRELU * e2);
      float e3 = s1v + s2v.w; e3 = fmaxf(e3, LRELU * e3);
      const float p0 = av.x > 0 ? __expf(e0 - mv) : 0.f;
      const float p1 = av.y > 0 ? __expf(e1 - mv) : 0.f;
      const float p2 = av.z > 0 ? __expf(e2 - mv) : 0.f;
      const float p3 = av.w > 0 ? __expf(e3 - mv) : 0.f;
      const int pb = il * PSTR + t4 * 4;
      pl[pb + 0] = p0;
      pl[pb + 1] = p1;
      pl[pb + 2] = p2;
      pl[pb + 3] = p3;
      lacc[c] += (p0 + p1) + (p2 + p3);
    }
    __syncthreads();

    // P @ H : 8x8 micro-tile per thread
#pragma unroll 2
    for (int k = 0; k < BJ; ++k) {
      const float4 h0 = *(const float4*)&hl[k * FOUT + tf * 8];
      const float4 h1 = *(const float4*)&hl[k * FOUT + tf * 8 + 4];
#pragma unroll
      for (int r = 0; r < 8; ++r) {
        const float p = pl[(tr * 8 + r) * PSTR + k];
        acc[r][0].x = fmaf(p, h0.x, acc[r][0].x);
        acc[r][0].y = fmaf(p, h0.y, acc[r][0].y);
        acc[r][0].z = fmaf(p, h0.z, acc[r][0].z);
        acc[r][0].w = fmaf(p, h0.w, acc[r][0].w);
        acc[r][1].x = fmaf(p, h1.x, acc[r][1].x);
        acc[r][1].y = fmaf(p, h1.y, acc[r][1].y);
        acc[r][1].z = fmaf(p, h1.z, acc[r][1].z);
        acc[r][1].w = fmaf(p, h1.w, acc[r][1].w);
      }
    }
    __syncthreads();
  }

  // l partials: reduce within aligned 16-lane groups (same i owner group)
#pragma unroll
  for (int c = 0; c < 16; ++c) {
    float v = lacc[c];
    v += __shfl_xor(v, 1);
    v += __shfl_xor(v, 2);
    v += __shfl_xor(v, 4);
    v += __shfl_xor(v, 8);
    if (t4 == 0) ws[WS_LP + js * NN + i0 + c * 8 + r16] = v;
  }

  // acc partials
  float* pacc = ws + WS_PACC + (size_t)js * (NN * FOUT);
#pragma unroll
  for (int r = 0; r < 8; ++r) {
    const size_t row = (size_t)(i0 + tr * 8 + r);
    *(float4*)&pacc[row * FOUT + tf * 8] = acc[r][0];
    *(float4*)&pacc[row * FOUT + tf * 8 + 4] = acc[r][1];
  }
}

// ---------------------------------------------------------------------------
// Kernel 4: combine j-split partials, normalize, ELU
// ---------------------------------------------------------------------------
__global__ __launch_bounds__(256) void k_combine(const float* __restrict__ ws,
                                                 float* __restrict__ out) {
  const int idx = blockIdx.x * 256 + threadIdx.x;
  const int i = idx >> 6;
  float s = 0.f, l = 0.f;
#pragma unroll
  for (int js = 0; js < JSPLIT; ++js) {
    s += ws[WS_PACC + (size_t)js * (NN * FOUT) + idx];
    l += ws[WS_LP + js * NN + i];
  }
  const float v = s / l;
  out[idx] = v > 0.f ? v : expm1f(v);
}

// ---------------------------------------------------------------------------
extern "C" void kernel_launch(void* const* d_in, const int* in_sizes, int n_in,
                              void* d_out, int out_size, void* d_ws,
                              size_t ws_size, hipStream_t stream) {
  const float* x = (const float*)d_in[0];
  const int* adj = (const int*)d_in[1];
  const float* W = (const float*)d_in[2];
  const float* a = (const float*)d_in[3];
  float* ws = (float*)d_ws;
  float* out = (float*)d_out;

  hipLaunchKernelGGL(k_hs, dim3(NN / 4), dim3(256), 0, stream, x, W, a, ws);
  hipLaunchKernelGGL(k_s2max, dim3(1), dim3(256), 0, stream, ws);
  hipLaunchKernelGGL(k_main, dim3((NN / BI) * JSPLIT), dim3(128), 0, stream,
                     adj, ws);
  hipLaunchKernelGGL(k_combine, dim3(NN * FOUT / 256), dim3(256), 0, stream,
                     ws, out);
}

// Round 2
// 414.061 us; speedup vs baseline: 1.2968x; 1.2968x over previous
//
#include <hip/hip_runtime.h>
#include <math.h>

#define NN 8192
#define FIN 128
#define FOUT 64
#define LRELU 0.2f
#define JSPLIT 8
#define BI 64
#define PASTR 72   // 64 + 8 halfs pad (144 B rows, 16B-aligned frag reads)
#define HTSTR 72

typedef _Float16 f16x8 __attribute__((ext_vector_type(8)));
typedef _Float16 f16x4 __attribute__((ext_vector_type(4)));
typedef float f32x4 __attribute__((ext_vector_type(4)));

// workspace layout (float offsets)
#define WS_HT 0                        // H^T as f16 [FOUT][NN] = 262144 floats
#define WS_S1 262144
#define WS_S2 270336
#define WS_S2MAX 278528
#define WS_PACC 278544                 // JSPLIT x NN x FOUT f32 partials
#define WS_LP (WS_PACC + JSPLIT * NN * FOUT)

// ---------------------------------------------------------------------------
// Kernel 1: h = x@W; emit s1=h@a1, s2=h@a2 (f32) and H^T (f16, [feat][row]).
// 512 blocks x 256 threads; 16 rows/block; thread = 1 row x 4 feats.
// ---------------------------------------------------------------------------
__global__ __launch_bounds__(256) void k_hs(const float* __restrict__ x,
                                            const float* __restrict__ W,
                                            const float* __restrict__ a,
                                            float* ws) {
  __shared__ float Wl[FIN * FOUT];   // 32 KB
  __shared__ float xl[16 * FIN];     // 8 KB
  __shared__ float hl[16 * FOUT];    // 4 KB
  const int t = threadIdx.x;
  const int i0 = blockIdx.x * 16;

#pragma unroll
  for (int c = 0; c < 8; ++c) {
    const int flat = c * 1024 + t * 4;
    *(float4*)&Wl[flat] = *(const float4*)&W[flat];
  }
#pragma unroll
  for (int c = 0; c < 2; ++c) {
    const int flat = c * 1024 + t * 4;
    *(float4*)&xl[flat] = *(const float4*)&x[(size_t)i0 * FIN + flat];
  }
  __syncthreads();

  const int r = t >> 4;     // local row 0..15
  const int fg = t & 15;    // feat group: feats [4*fg, 4*fg+4)
  float4 acc = make_float4(0.f, 0.f, 0.f, 0.f);
#pragma unroll 4
  for (int k = 0; k < FIN; ++k) {
    const float xv = xl[r * FIN + k];
    const float4 wv = *(const float4*)&Wl[k * FOUT + fg * 4];
    acc.x = fmaf(xv, wv.x, acc.x);
    acc.y = fmaf(xv, wv.y, acc.y);
    acc.z = fmaf(xv, wv.z, acc.z);
    acc.w = fmaf(xv, wv.w, acc.w);
  }

  // s1/s2 via 16-lane reduction (lanes fg share row r)
  float v1 = acc.x * a[fg * 4] + acc.y * a[fg * 4 + 1] +
             acc.z * a[fg * 4 + 2] + acc.w * a[fg * 4 + 3];
  float v2 = acc.x * a[FOUT + fg * 4] + acc.y * a[FOUT + fg * 4 + 1] +
             acc.z * a[FOUT + fg * 4 + 2] + acc.w * a[FOUT + fg * 4 + 3];
  v1 += __shfl_xor(v1, 1); v2 += __shfl_xor(v2, 1);
  v1 += __shfl_xor(v1, 2); v2 += __shfl_xor(v2, 2);
  v1 += __shfl_xor(v1, 4); v2 += __shfl_xor(v2, 4);
  v1 += __shfl_xor(v1, 8); v2 += __shfl_xor(v2, 8);
  if (fg == 0) {
    ws[WS_S1 + i0 + r] = v1;
    ws[WS_S2 + i0 + r] = v2;
  }

  // transpose h tile -> H^T (f16) via LDS
  *(float4*)&hl[r * FOUT + fg * 4] = acc;
  __syncthreads();
  _Float16* ht = (_Float16*)(ws + WS_HT);
  if (t < 128) {
    const int f = t >> 1;
    const int off = (t & 1) * 8;
    f16x8 tmp;
#pragma unroll
    for (int u = 0; u < 8; ++u) tmp[u] = (_Float16)hl[(off + u) * FOUT + f];
    *(f16x8*)&ht[(size_t)f * NN + i0 + off] = tmp;
  }
}

// ---------------------------------------------------------------------------
// Kernel 2: S2max = max_j s2[j]  (leaky is monotone -> closed-form row max)
// ---------------------------------------------------------------------------
__global__ __launch_bounds__(256) void k_s2max(float* ws) {
  __shared__ float red[256];
  const int t = threadIdx.x;
  float v = -1e30f;
#pragma unroll
  for (int i = 0; i < NN / 256; ++i) v = fmaxf(v, ws[WS_S2 + i * 256 + t]);
  red[t] = v;
  __syncthreads();
  for (int s = 128; s >= 1; s >>= 1) {
    if (t < s) red[t] = fmaxf(red[t], red[t + s]);
    __syncthreads();
  }
  if (t == 0) ws[WS_S2MAX] = red[0];
}

// ---------------------------------------------------------------------------
// Kernel 3: fused masked-softmax-numerator + P@H via f16 MFMA.
// Grid: 128 i-tiles x JSPLIT(8) = 1024 blocks, 256 threads (4 waves).
// Per 64-j tile: adj int4 -> p (f16, A-frag layout LDS); ht tile staged;
// wave w computes rows w*16..+15 x all 64 feats: 8x mfma_f32_16x16x32_f16.
// ---------------------------------------------------------------------------
__global__ __launch_bounds__(256) void k_main(const int* __restrict__ adj,
                                              float* ws) {
  __shared__ __align__(16) _Float16 pal[BI * PASTR];   // 9.2 KB
  __shared__ __align__(16) _Float16 htl[FOUT * HTSTR]; // 9.2 KB
  __shared__ float s1l[BI], mll[BI];

  const int t = threadIdx.x;
  const int ib = blockIdx.x >> 3;
  const int js = blockIdx.x & 7;
  const int i0 = ib * BI;
  const int jbase = js * (NN / JSPLIT);   // 1024-wide j-chunk

  const _Float16* ht = (const _Float16*)(ws + WS_HT);
  const float s2max = ws[WS_S2MAX];
  if (t < BI) {
    const float s1v = ws[WS_S1 + i0 + t];
    s1l[t] = s1v;
    const float tmp = s1v + s2max;
    mll[t] = fmaxf(tmp, LRELU * tmp);   // leaky = max(x, 0.2x)
  }

  f32x4 acc[4];
#pragma unroll
  for (int nf = 0; nf < 4; ++nf) acc[nf] = (f32x4){0.f, 0.f, 0.f, 0.f};
  float lacc[4] = {0.f, 0.f, 0.f, 0.f};

  const int jg = t & 15;   // j-group: 4 consecutive j
  const int ig = t >> 4;   // 0..15 (row within 16-row band)
  const int w = t >> 6;    // wave
  const int l = t & 63;    // lane

  __syncthreads();

  for (int tile = 0; tile < (NN / JSPLIT) / 64; ++tile) {  // 16 tiles
    const int j0 = jbase + tile * 64;

    // stage ht tile: 64 feats x 64 halfs, 16B chunks
#pragma unroll
    for (int c2 = 0; c2 < 2; ++c2) {
      const int chunk = t + c2 * 256;
      const int n = chunk >> 3, off = (chunk & 7) * 8;
      *(f16x8*)&htl[n * HTSTR + off] = *(const f16x8*)&ht[(size_t)n * NN + j0 + off];
    }

    // p tile: thread covers 4 rows x 4 consecutive j
    const float4 s2v = *(const float4*)&ws[WS_S2 + j0 + jg * 4];
#pragma unroll
    for (int c = 0; c < 4; ++c) {
      const int il = ig + c * 16;
      const int4 av = *(const int4*)&adj[(size_t)(i0 + il) * NN + j0 + jg * 4];
      const float s1v = s1l[il], mv = mll[il];
      float e0 = s1v + s2v.x; e0 = fmaxf(e0, LRELU * e0);
      float e1 = s1v + s2v.y; e1 = fmaxf(e1, LRELU * e1);
      float e2 = s1v + s2v.z; e2 = fmaxf(e2, LRELU * e2);
      float e3 = s1v + s2v.w; e3 = fmaxf(e3, LRELU * e3);
      const _Float16 p0 = av.x > 0 ? (_Float16)__expf(e0 - mv) : (_Float16)0.f;
      const _Float16 p1 = av.y > 0 ? (_Float16)__expf(e1 - mv) : (_Float16)0.f;
      const _Float16 p2 = av.z > 0 ? (_Float16)__expf(e2 - mv) : (_Float16)0.f;
      const _Float16 p3 = av.w > 0 ? (_Float16)__expf(e3 - mv) : (_Float16)0.f;
      // denominator from f16-rounded p: cancels p-rounding in the ratio
      lacc[c] += ((float)p0 + (float)p1) + ((float)p2 + (float)p3);
      f16x4 pv = {p0, p1, p2, p3};
      *(f16x4*)&pal[il * PASTR + jg * 4] = pv;
    }
    __syncthreads();

    // MFMA: A[m=lane&15][k=quad*8+j], B[k=quad*8+j][n=lane&15]
    {
      const int mrow = w * 16 + (l & 15);
      const int q8 = (l >> 4) * 8;
      const f16x8 a0 = *(const f16x8*)&pal[mrow * PASTR + q8];
      const f16x8 a1 = *(const f16x8*)&pal[mrow * PASTR + 32 + q8];
#pragma unroll
      for (int nf = 0; nf < 4; ++nf) {
        const int nrow = nf * 16 + (l & 15);
        const f16x8 b0 = *(const f16x8*)&htl[nrow * HTSTR + q8];
        const f16x8 b1 = *(const f16x8*)&htl[nrow * HTSTR + 32 + q8];
        acc[nf] = __builtin_amdgcn_mfma_f32_16x16x32_f16(a0, b0, acc[nf], 0, 0, 0);
        acc[nf] = __builtin_amdgcn_mfma_f32_16x16x32_f16(a1, b1, acc[nf], 0, 0, 0);
      }
    }
    __syncthreads();
  }

  // l partials: reduce over the 16 j-group lanes
#pragma unroll
  for (int c = 0; c < 4; ++c) {
    float v = lacc[c];
    v += __shfl_xor(v, 1);
    v += __shfl_xor(v, 2);
    v += __shfl_xor(v, 4);
    v += __shfl_xor(v, 8);
    if (jg == 0) ws[WS_LP + js * NN + i0 + ig + c * 16] = v;
  }

  // acc partials: C/D layout col=lane&15, row=(lane>>4)*4+reg
  float* pacc = ws + WS_PACC + (size_t)js * (NN * FOUT);
  const int orow = i0 + w * 16 + (l >> 4) * 4;
  const int ocol = l & 15;
#pragma unroll
  for (int nf = 0; nf < 4; ++nf)
#pragma unroll
    for (int r = 0; r < 4; ++r)
      pacc[(size_t)(orow + r) * FOUT + nf * 16 + ocol] = acc[nf][r];
}

// ---------------------------------------------------------------------------
// Kernel 4: combine j-split partials, normalize, ELU
// ---------------------------------------------------------------------------
__global__ __launch_bounds__(256) void k_combine(const float* __restrict__ ws,
                                                 float* __restrict__ out) {
  const int idx = blockIdx.x * 256 + threadIdx.x;
  const int i = idx >> 6;
  float s = 0.f, l = 0.f;
#pragma unroll
  for (int js = 0; js < JSPLIT; ++js) {
    s += ws[WS_PACC + (size_t)js * (NN * FOUT) + idx];
    l += ws[WS_LP + js * NN + i];
  }
  const float v = s / l;
  out[idx] = v > 0.f ? v : expm1f(v);
}

// ---------------------------------------------------------------------------
extern "C" void kernel_launch(void* const* d_in, const int* in_sizes, int n_in,
                              void* d_out, int out_size, void* d_ws,
                              size_t ws_size, hipStream_t stream) {
  const float* x = (const float*)d_in[0];
  const int* adj = (const int*)d_in[1];
  const float* W = (const float*)d_in[2];
  const float* a = (const float*)d_in[3];
  float* ws = (float*)d_ws;
  float* out = (float*)d_out;

  hipLaunchKernelGGL(k_hs, dim3(NN / 16), dim3(256), 0, stream, x, W, a, ws);
  hipLaunchKernelGGL(k_s2max, dim3(1), dim3(256), 0, stream, ws);
  hipLaunchKernelGGL(k_main, dim3((NN / BI) * JSPLIT), dim3(256), 0, stream,
                     adj, ws);
  hipLaunchKernelGGL(k_combine, dim3(NN * FOUT / 256), dim3(256), 0, stream,
                     ws, out);
}

// Round 3
// 391.066 us; speedup vs baseline: 1.3731x; 1.0588x over previous
//
#include <hip/hip_runtime.h>
#include <math.h>

#define NN 8192
#define FIN 128
#define FOUT 64
#define LRELU 0.2f
#define JSPLIT 16
#define JCH (NN / JSPLIT)   // 512
#define HTSTR 520           // halfs; word-stride 260 = 4 mod 32 -> balanced b128 banks
#define L2E 1.44269504f

typedef _Float16 f16x8 __attribute__((ext_vector_type(8)));
typedef float f32x4 __attribute__((ext_vector_type(4)));

// workspace layout (float offsets)
#define WS_HT 0                        // H^T as f16 [FOUT][NN] = 262144 floats
#define WS_S1 262144
#define WS_S2 270336
#define WS_S2MAX 278528
#define WS_PACC 278544                 // JSPLIT x NN x FOUT f32 partials (32 MB)
#define WS_LP (WS_PACC + JSPLIT * NN * FOUT)

// ---------------------------------------------------------------------------
// Kernel 1: h = x@W; emit s1=h@a1, s2=h@a2 (f32) and H^T (f16, [feat][row]).
// ---------------------------------------------------------------------------
__global__ __launch_bounds__(256) void k_hs(const float* __restrict__ x,
                                            const float* __restrict__ W,
                                            const float* __restrict__ a,
                                            float* ws) {
  __shared__ float Wl[FIN * FOUT];   // 32 KB
  __shared__ float xl[16 * FIN];     // 8 KB
  __shared__ float hl[16 * FOUT];    // 4 KB
  const int t = threadIdx.x;
  const int i0 = blockIdx.x * 16;

#pragma unroll
  for (int c = 0; c < 8; ++c) {
    const int flat = c * 1024 + t * 4;
    *(float4*)&Wl[flat] = *(const float4*)&W[flat];
  }
#pragma unroll
  for (int c = 0; c < 2; ++c) {
    const int flat = c * 1024 + t * 4;
    *(float4*)&xl[flat] = *(const float4*)&x[(size_t)i0 * FIN + flat];
  }
  __syncthreads();

  const int r = t >> 4;     // local row 0..15
  const int fg = t & 15;    // feat group: feats [4*fg, 4*fg+4)
  float4 acc = make_float4(0.f, 0.f, 0.f, 0.f);
#pragma unroll 4
  for (int k = 0; k < FIN; ++k) {
    const float xv = xl[r * FIN + k];
    const float4 wv = *(const float4*)&Wl[k * FOUT + fg * 4];
    acc.x = fmaf(xv, wv.x, acc.x);
    acc.y = fmaf(xv, wv.y, acc.y);
    acc.z = fmaf(xv, wv.z, acc.z);
    acc.w = fmaf(xv, wv.w, acc.w);
  }

  float v1 = acc.x * a[fg * 4] + acc.y * a[fg * 4 + 1] +
             acc.z * a[fg * 4 + 2] + acc.w * a[fg * 4 + 3];
  float v2 = acc.x * a[FOUT + fg * 4] + acc.y * a[FOUT + fg * 4 + 1] +
             acc.z * a[FOUT + fg * 4 + 2] + acc.w * a[FOUT + fg * 4 + 3];
  v1 += __shfl_xor(v1, 1); v2 += __shfl_xor(v2, 1);
  v1 += __shfl_xor(v1, 2); v2 += __shfl_xor(v2, 2);
  v1 += __shfl_xor(v1, 4); v2 += __shfl_xor(v2, 4);
  v1 += __shfl_xor(v1, 8); v2 += __shfl_xor(v2, 8);
  if (fg == 0) {
    ws[WS_S1 + i0 + r] = v1;
    ws[WS_S2 + i0 + r] = v2;
  }

  // transpose h tile -> H^T (f16) via LDS
  *(float4*)&hl[r * FOUT + fg * 4] = acc;
  __syncthreads();
  _Float16* ht = (_Float16*)(ws + WS_HT);
  if (t < 128) {
    const int f = t >> 1;
    const int off = (t & 1) * 8;
    f16x8 tmp;
#pragma unroll
    for (int u = 0; u < 8; ++u) tmp[u] = (_Float16)hl[(off + u) * FOUT + f];
    *(f16x8*)&ht[(size_t)f * NN + i0 + off] = tmp;
  }
}

// ---------------------------------------------------------------------------
// Kernel 2: S2max = max_j s2[j]  (leaky monotone -> closed-form row max)
// ---------------------------------------------------------------------------
__global__ __launch_bounds__(256) void k_s2max(float* ws) {
  __shared__ float red[256];
  const int t = threadIdx.x;
  float v = -1e30f;
#pragma unroll
  for (int i = 0; i < NN / 256; ++i) v = fmaxf(v, ws[WS_S2 + i * 256 + t]);
  red[t] = v;
  __syncthreads();
  for (int s = 128; s >= 1; s >>= 1) {
    if (t < s) red[t] = fmaxf(red[t], red[t + s]);
    __syncthreads();
  }
  if (t == 0) ws[WS_S2MAX] = red[0];
}

// ---------------------------------------------------------------------------
// Kernel 3: barrier-free streaming pass.
// Grid: 64 i-blocks x 16 j-splits = 1024 blocks, 512 thr (8 waves).
// Wave w owns 16-row band; lane computes its MFMA A-frag p-values directly
// in registers from its own adj loads (A[m=l&15][k=q*8+u]). H^T j-chunk
// (512 wide, f16) + s2 staged in LDS once; j-loop has NO barriers.
// ---------------------------------------------------------------------------
__global__ __launch_bounds__(512, 1) void k_main(const int* __restrict__ adj,
                                                 float* ws) {
  __shared__ __align__(16) _Float16 htl[FOUT * HTSTR];  // 66560 B
  __shared__ float s2l[JCH];                            // 2 KB

  const int t = threadIdx.x;
  const int ib = blockIdx.x >> 4;
  const int js = blockIdx.x & 15;
  const int i0 = ib * 128;
  const int jc0 = js * JCH;

  const _Float16* ht = (const _Float16*)(ws + WS_HT);

  // stage H^T chunk: 64 feats x 512 halfs, coalesced 16B
#pragma unroll
  for (int c = 0; c < 8; ++c) {
    const int chunk = c * 512 + t;      // 0..4095
    const int f = chunk >> 6;
    const int off = (chunk & 63) * 8;
    *(f16x8*)&htl[f * HTSTR + off] = *(const f16x8*)&ht[(size_t)f * NN + jc0 + off];
  }
  s2l[t] = ws[WS_S2 + jc0 + t];   // JCH == blockDim == 512

  const int w = t >> 6;     // wave 0..7
  const int l = t & 63;
  const int m16 = l & 15;
  const int q8 = (l >> 4) * 8;
  const int row = i0 + w * 16 + m16;

  const float s2max = ws[WS_S2MAX];
  const float s1v = ws[WS_S1 + row];
  const float tmp0 = s1v + s2max;
  const float mv = fmaxf(tmp0, LRELU * tmp0);
  const float mneg = -mv * L2E;

  f32x4 acc[4];
#pragma unroll
  for (int nf = 0; nf < 4; ++nf) acc[nf] = (f32x4){0.f, 0.f, 0.f, 0.f};
  float lacc = 0.f;

  const int* arow = adj + (size_t)row * NN + jc0 + q8;

  __syncthreads();   // the only barrier

#pragma unroll 2
  for (int it = 0; it < JCH / 32; ++it) {   // 16 iterations
    const int4 a0 = *(const int4*)(arow + it * 32);
    const int4 a1 = *(const int4*)(arow + it * 32 + 4);
    const float4 s20 = *(const float4*)&s2l[it * 32 + q8];
    const float4 s21 = *(const float4*)&s2l[it * 32 + q8 + 4];

    float e, p[8];
    e = s1v + s20.x; e = fmaxf(e, LRELU * e); p[0] = a0.x ? exp2f(fmaf(e, L2E, mneg)) : 0.f;
    e = s1v + s20.y; e = fmaxf(e, LRELU * e); p[1] = a0.y ? exp2f(fmaf(e, L2E, mneg)) : 0.f;
    e = s1v + s20.z; e = fmaxf(e, LRELU * e); p[2] = a0.z ? exp2f(fmaf(e, L2E, mneg)) : 0.f;
    e = s1v + s20.w; e = fmaxf(e, LRELU * e); p[3] = a0.w ? exp2f(fmaf(e, L2E, mneg)) : 0.f;
    e = s1v + s21.x; e = fmaxf(e, LRELU * e); p[4] = a1.x ? exp2f(fmaf(e, L2E, mneg)) : 0.f;
    e = s1v + s21.y; e = fmaxf(e, LRELU * e); p[5] = a1.y ? exp2f(fmaf(e, L2E, mneg)) : 0.f;
    e = s1v + s21.z; e = fmaxf(e, LRELU * e); p[6] = a1.z ? exp2f(fmaf(e, L2E, mneg)) : 0.f;
    e = s1v + s21.w; e = fmaxf(e, LRELU * e); p[7] = a1.w ? exp2f(fmaf(e, L2E, mneg)) : 0.f;

    f16x8 af;
#pragma unroll
    for (int u = 0; u < 8; ++u) af[u] = (_Float16)p[u];
    // denominator from the f16-rounded p: cancels rounding in the ratio
#pragma unroll
    for (int u = 0; u < 8; ++u) lacc += (float)af[u];

    const int kb = it * 32 + q8;
#pragma unroll
    for (int nf = 0; nf < 4; ++nf) {
      const f16x8 b = *(const f16x8*)&htl[(nf * 16 + m16) * HTSTR + kb];
      acc[nf] = __builtin_amdgcn_mfma_f32_16x16x32_f16(af, b, acc[nf], 0, 0, 0);
    }
  }

  // row-sum partial: reduce lacc across the 4 quads (same m16)
  lacc += __shfl_xor(lacc, 16);
  lacc += __shfl_xor(lacc, 32);
  if (l < 16) ws[WS_LP + js * NN + row] = lacc;

  // acc partials: C/D layout col=lane&15, row=(lane>>4)*4+reg
  float* pacc = ws + WS_PACC + (size_t)js * (NN * FOUT);
  const int orow = i0 + w * 16 + (l >> 4) * 4;
  const int ocol = m16;
#pragma unroll
  for (int nf = 0; nf < 4; ++nf)
#pragma unroll
    for (int r = 0; r < 4; ++r)
      pacc[(size_t)(orow + r) * FOUT + nf * 16 + ocol] = acc[nf][r];
}

// ---------------------------------------------------------------------------
// Kernel 4: combine j-split partials, normalize, ELU
// ---------------------------------------------------------------------------
__global__ __launch_bounds__(256) void k_combine(const float* __restrict__ ws,
                                                 float* __restrict__ out) {
  const int idx = blockIdx.x * 256 + threadIdx.x;
  const int i = idx >> 6;
  float s = 0.f, l = 0.f;
#pragma unroll
  for (int js = 0; js < JSPLIT; ++js) {
    s += ws[WS_PACC + (size_t)js * (NN * FOUT) + idx];
    l += ws[WS_LP + js * NN + i];
  }
  const float v = s / l;
  out[idx] = v > 0.f ? v : expm1f(v);
}

// ---------------------------------------------------------------------------
extern "C" void kernel_launch(void* const* d_in, const int* in_sizes, int n_in,
                              void* d_out, int out_size, void* d_ws,
                              size_t ws_size, hipStream_t stream) {
  const float* x = (const float*)d_in[0];
  const int* adj = (const int*)d_in[1];
  const float* W = (const float*)d_in[2];
  const float* a = (const float*)d_in[3];
  float* ws = (float*)d_ws;
  float* out = (float*)d_out;

  hipLaunchKernelGGL(k_hs, dim3(NN / 16), dim3(256), 0, stream, x, W, a, ws);
  hipLaunchKernelGGL(k_s2max, dim3(1), dim3(256), 0, stream, ws);
  hipLaunchKernelGGL(k_main, dim3((NN / 128) * JSPLIT), dim3(512), 0, stream,
                     adj, ws);
  hipLaunchKernelGGL(k_combine, dim3(NN * FOUT / 256), dim3(256), 0, stream,
                     ws, out);
}